// Round 8
// baseline (808.148 us; speedup 1.0000x reference)
//
#include <hip/hip_runtime.h>
#include <hip/hip_bf16.h>

// PTV3 attention: sort -> gather+bf16 prepass -> bf16 QKV GEMM -> flash MHA
// (online softmax, swapped QK^T, direct-from-L2 K/V, defer-max, scattered
// write) -> bf16 proj GEMM. GEMMs: m97 + T2 swizzle + coalesced Vt epilogue.

typedef unsigned long long u64;
typedef unsigned short ushort_t;
typedef __attribute__((ext_vector_type(8))) short short8v;
typedef __attribute__((ext_vector_type(4))) float f32x4;

#define MFMA_BF16 __builtin_amdgcn_mfma_f32_16x16x32_bf16

__device__ __forceinline__ unsigned short f2bf(float f) {
  union { float f; unsigned u; } v; v.f = f;
  return (unsigned short)((v.u + 0x7FFFu + ((v.u >> 16) & 1u)) >> 16);
}

__device__ __forceinline__ unsigned pk2(float a, float b) {
  __hip_bfloat162 h = __float22bfloat162_rn(float2{a, b});
  unsigned u; __builtin_memcpy(&u, &h, 4); return u;
}

// async global->LDS, 16B per lane; LDS dest = wave-uniform base + lane*16
__device__ __forceinline__ void async16(ushort_t* lds, const ushort_t* g) {
  __builtin_amdgcn_global_load_lds(
      (const __attribute__((address_space(1))) unsigned int*)g,
      (__attribute__((address_space(3))) unsigned int*)lds, 16, 0, 0);
}

// ---------------- stable sort of (code, idx) per 16384-group ----------------

__global__ __launch_bounds__(512) void sort_chunk(const int* __restrict__ codes,
                                                  u64* __restrict__ keys) {
  __shared__ u64 sk[4096];
  const int base = blockIdx.x * 4096;
  for (int t = threadIdx.x; t < 4096; t += 512) {
    int e = base + t;
    sk[t] = (((u64)(unsigned)codes[e]) << 14) | (u64)(e & 16383);
  }
  __syncthreads();
  for (int k = 2; k <= 4096; k <<= 1) {
    for (int j = k >> 1; j > 0; j >>= 1) {
      for (int t = threadIdx.x; t < 4096; t += 512) {
        int jx = t ^ j;
        if (jx > t) {
          bool up = (((base + t) & 16383 & k) == 0);
          u64 a = sk[t], b = sk[jx];
          if ((a > b) == up) { sk[t] = b; sk[jx] = a; }
        }
      }
      __syncthreads();
    }
  }
  for (int t = threadIdx.x; t < 4096; t += 512) keys[base + t] = sk[t];
}

__global__ __launch_bounds__(256) void sort_gpass(u64* __restrict__ keys, int k, int j) {
  int t = blockIdx.x * 256 + threadIdx.x;
  int jx = t ^ j;
  if (jx > t) {
    bool up = ((t & 16383 & k) == 0);
    u64 a = keys[t], b = keys[jx];
    if ((a > b) == up) { keys[t] = b; keys[jx] = a; }
  }
}

__global__ __launch_bounds__(512) void sort_finish(u64* __restrict__ keys, int k) {
  __shared__ u64 sk[4096];
  const int base = blockIdx.x * 4096;
  for (int t = threadIdx.x; t < 4096; t += 512) sk[t] = keys[base + t];
  __syncthreads();
  for (int j = 2048; j > 0; j >>= 1) {
    for (int t = threadIdx.x; t < 4096; t += 512) {
      int jx = t ^ j;
      if (jx > t) {
        bool up = (((base + t) & 16383 & k) == 0);
        u64 a = sk[t], b = sk[jx];
        if ((a > b) == up) { sk[t] = b; sk[jx] = a; }
      }
    }
    __syncthreads();
  }
  for (int t = threadIdx.x; t < 4096; t += 512) keys[base + t] = sk[t];
}

__global__ __launch_bounds__(256) void write_perm(const u64* __restrict__ keys,
                                                  int* __restrict__ perm) {
  int t = blockIdx.x * 256 + threadIdx.x;
  int g = t >> 14;
  int a = (int)(keys[t] & 16383);
  perm[t] = (g << 14) | a;        // perm[sorted pos] = original row
}

// ---------------- prepass: Abf[m][k] = bf16(feats[perm[m]][k]) ----------------

__global__ __launch_bounds__(256) void gather_bf16(const float* __restrict__ feats,
    const int* __restrict__ perm, ushort_t* __restrict__ A) {
  int t = blockIdx.x * 256 + threadIdx.x;
  int m = t >> 5;
  int off = (t & 31) << 4;
  const float* src = feats + (size_t)perm[m] * 512 + off;
  float4 a = ((const float4*)src)[0];
  float4 b = ((const float4*)src)[1];
  float4 c = ((const float4*)src)[2];
  float4 d = ((const float4*)src)[3];
  short8v lo = { (short)f2bf(a.x), (short)f2bf(a.y), (short)f2bf(a.z), (short)f2bf(a.w),
                 (short)f2bf(b.x), (short)f2bf(b.y), (short)f2bf(b.z), (short)f2bf(b.w) };
  short8v hi = { (short)f2bf(c.x), (short)f2bf(c.y), (short)f2bf(c.z), (short)f2bf(c.w),
                 (short)f2bf(d.x), (short)f2bf(d.y), (short)f2bf(d.z), (short)f2bf(d.w) };
  ushort_t* dst = A + (size_t)m * 512 + off;
  *(short8v*)(dst) = lo;
  *(short8v*)(dst + 8) = hi;
}

__global__ __launch_bounds__(256) void convert_bf16(const float* __restrict__ src,
                                                    ushort_t* __restrict__ dst) {
  int t = blockIdx.x * 256 + threadIdx.x;
  const float* s = src + (size_t)t * 8;
  float4 a = ((const float4*)s)[0];
  float4 b = ((const float4*)s)[1];
  short8v v = { (short)f2bf(a.x), (short)f2bf(a.y), (short)f2bf(a.z), (short)f2bf(a.w),
                (short)f2bf(b.x), (short)f2bf(b.y), (short)f2bf(b.z), (short)f2bf(b.w) };
  *(short8v*)(dst + (size_t)t * 8) = v;
}

// ---------------- QKV GEMM (bf16), T2-swizzled LDS ----------------
// LDS content: lds(row, slot16) = g(row, slot16 ^ (row&7)); involution on both sides.

__global__ __launch_bounds__(256) void qkv_gemm(const ushort_t* __restrict__ A,
    const ushort_t* __restrict__ W, const float* __restrict__ bias,
    ushort_t* __restrict__ Q, ushort_t* __restrict__ Ko, ushort_t* __restrict__ Vt)
{
  __shared__ __align__(16) ushort_t la[128 * 64];
  __shared__ __align__(16) ushort_t lb[128 * 64];
  const int bid = blockIdx.x;                 // 6144 = 12 x 512, XCD-chunked
  const int swz = (bid & 7) * 768 + (bid >> 3);
  const int bx = swz % 12, by = swz / 12;
  const int rowBase = by * 128, colBase = bx * 128;
  const int tid = threadIdx.x, lane = tid & 63, w = tid >> 6;
  const int wr = w >> 1, wc = w & 1;
  const int li = lane & 15, kb = lane >> 4;
  const int lr = lane >> 3;
  const int lcs = (((lane & 7) ^ lr) << 3);   // pre-swizzled source col (elems)
  f32x4 acc[4][4] = {};
  for (int kt = 0; kt < 8; ++kt) {
#pragma unroll
    for (int i = 0; i < 4; ++i) {
      int c = w * 4 + i;
      async16(la + c * 512, A + (size_t)(rowBase + c * 8 + lr) * 512 + kt * 64 + lcs);
      async16(lb + c * 512, W + (size_t)(colBase + c * 8 + lr) * 512 + kt * 64 + lcs);
    }
    __syncthreads();
    short8v af[2][4], bfr[2][4];
#pragma unroll
    for (int kk = 0; kk < 2; ++kk)
#pragma unroll
      for (int t = 0; t < 4; ++t) {
        int sl = ((kk * 4 + kb) ^ (li & 7)) << 3;   // swizzled read slot
        af[kk][t]  = *(const short8v*)(la + (wr * 64 + t * 16 + li) * 64 + sl);
        bfr[kk][t] = *(const short8v*)(lb + (wc * 64 + t * 16 + li) * 64 + sl);
      }
#pragma unroll
    for (int kk = 0; kk < 2; ++kk)
#pragma unroll
      for (int i = 0; i < 4; ++i)
#pragma unroll
        for (int j = 0; j < 4; ++j)
          acc[i][j] = MFMA_BF16(af[kk][i], bfr[kk][j], acc[i][j], 0, 0, 0);
    __syncthreads();
  }
  const int c0 = colBase + wc * 64;           // wave's first global col
  if (c0 >= 1024) {
    // ---- V block: transpose 64x64 subtile via private LDS, store p-contiguous ----
    ushort_t* tw = (w < 2) ? (la + w * 4096) : (lb + (w - 2) * 4096);
    char* twb = (char*)tw;
#pragma unroll
    for (int j = 0; j < 4; ++j) {
      int dloc = j * 16 + li;
      float bv = bias[c0 + dloc];
#pragma unroll
      for (int i = 0; i < 4; ++i) {
        unsigned u0 = pk2(acc[i][j][0] + bv, acc[i][j][1] + bv);
        unsigned u1 = pk2(acc[i][j][2] + bv, acc[i][j][3] + bv);
        int s = i * 2 + (kb >> 1);
        int byte = dloc * 128 + ((s ^ (dloc & 7)) << 4) + ((kb & 1) << 3);
        *(uint2*)(twb + byte) = make_uint2(u0, u1);
      }
    }
    const int h = (c0 - 1024) >> 6;
    const size_t nh = (size_t)((rowBase >> 9) * 8 + h);
    const int pbase = ((rowBase + wr * 64) & 511) + ((lane & 7) << 3);
    ushort_t* vb = Vt + nh * 32768 + pbase;
#pragma unroll
    for (int ps = 0; ps < 8; ++ps) {
      int dloc = ps * 8 + (lane >> 3);
      int byte = dloc * 128 + ((((lane & 7)) ^ (dloc & 7)) << 4);
      short8v vv = *(const short8v*)(twb + byte);
      *(short8v*)(vb + dloc * 512) = vv;
    }
  } else {
    // ---- Q/K block: original store path ----
#pragma unroll
    for (int j = 0; j < 4; ++j) {
      int colb = c0 + j * 16;
      int col = colb + li;
      float bv = bias[col];
      int c3 = colb >> 9;
      int h = (col >> 6) & 7;
      int d = col & 63;
#pragma unroll
      for (int i = 0; i < 4; ++i) {
        int m0 = rowBase + wr * 64 + i * 16 + kb * 4;
#pragma unroll
        for (int r = 0; r < 4; ++r) {
          int m = m0 + r;
          int n = m >> 9, p = m & 511;
          unsigned short bv16 = f2bf(acc[i][j][r] + bv);
          size_t nh = (size_t)(n * 8 + h);
          if (c3 == 0) Q [(nh * 512 + p) * 64 + d] = bv16;
          else         Ko[(nh * 512 + p) * 64 + d] = bv16;
        }
      }
    }
  }
}

// ---------------- flash attention: direct-from-L2 K/V, no barriers ----------------
// wave = 16 q-rows. Swapped QK^T; k-reduce lane-local + 2 shfl. K/V chunks are
// 8KB, L1/L2-resident and shared by all 4 waves + 8 qc-blocks -> no LDS staging.
// Defer-max (T13, THR=16 raw units -> P <= e^2): skip rescale when max stable.

__global__ __launch_bounds__(256) void attn_kernel(const ushort_t* __restrict__ Q,
    const ushort_t* __restrict__ K, const ushort_t* __restrict__ Vt,
    const int* __restrict__ perm, ushort_t* __restrict__ O)
{
  __shared__ __align__(16) ushort_t pbuf[4][16][72];
  const int b = blockIdx.x;
  const int qc = (b >> 3) & 7;
  const int nh = ((b >> 6) << 3) | (b & 7);
  const int n = nh >> 3, h = nh & 7;
  const int tid = threadIdx.x, w = tid >> 6, lane = tid & 63;
  const int li = lane & 15, kb = lane >> 4;
  const ushort_t* Qb = Q + (size_t)nh * (512 * 64);
  const ushort_t* Kl = K + (size_t)nh * (512 * 64) + li * 64 + kb * 8;
  const ushort_t* Vl = Vt + (size_t)nh * (64 * 512) + li * 512 + kb * 8;
  const int p0 = qc * 64 + w * 16;

  short8v qf0 = *(const short8v*)(Qb + (size_t)(p0 + li) * 64 + kb * 8);
  short8v qf1 = *(const short8v*)(Qb + (size_t)(p0 + li) * 64 + 32 + kb * 8);

  f32x4 o[4] = {};
  float m = -1e30f, l = 0.f;
  const float cs = 0.125f * 1.44269504088896340736f;  // scale * log2(e)

#pragma unroll
  for (int ch = 0; ch < 8; ++ch) {
    // QK^T straight from global (L1/L2 hit): S[k=16t+4kb+r][q=li]
    f32x4 s4[4];
#pragma unroll
    for (int t = 0; t < 4; ++t) {
      short8v kf0 = *(const short8v*)(Kl + ch * 4096 + t * 1024);
      short8v kf1 = *(const short8v*)(Kl + ch * 4096 + t * 1024 + 32);
      f32x4 z = {0.f, 0.f, 0.f, 0.f};
      z = MFMA_BF16(kf0, qf0, z, 0, 0, 0);
      z = MFMA_BF16(kf1, qf1, z, 0, 0, 0);
      s4[t] = z;
    }
    // chunk max per q (max3-friendly tree), then cross-kb reduce
    float ta = fmaxf(fmaxf(s4[0][0], s4[0][1]), s4[0][2]);
    float tb = fmaxf(fmaxf(s4[0][3], s4[1][0]), s4[1][1]);
    float tc = fmaxf(fmaxf(s4[1][2], s4[1][3]), s4[2][0]);
    float td = fmaxf(fmaxf(s4[2][1], s4[2][2]), s4[2][3]);
    float te = fmaxf(fmaxf(s4[3][0], s4[3][1]), s4[3][2]);
    float pm = fmaxf(fmaxf(fmaxf(ta, tb), fmaxf(tc, td)), fmaxf(te, s4[3][3]));
    pm = fmaxf(pm, __shfl_xor(pm, 16, 64));
    pm = fmaxf(pm, __shfl_xor(pm, 32, 64));
    // defer-max: only rescale when max grew past THR
    float scv = 1.0f;
    if (!__all(pm <= m + 16.0f)) {
      float mn = fmaxf(m, pm);
      scv = exp2f((m - mn) * cs);
      m = mn;
      float sr4[4];
#pragma unroll
      for (int r = 0; r < 4; ++r) sr4[r] = __shfl(scv, ((lane >> 4) << 2) + r, 16);
#pragma unroll
      for (int dt = 0; dt < 4; ++dt)
#pragma unroll
        for (int r = 0; r < 4; ++r) o[dt][r] *= sr4[r];
    }
    const float nm = -m * cs;
    float rs = 0.f;
#pragma unroll
    for (int t = 0; t < 4; ++t)
#pragma unroll
      for (int r = 0; r < 4; ++r) {
        float ev = exp2f(fmaf(s4[t][r], cs, nm));
        s4[t][r] = ev;
        rs += ev;
      }
    rs += __shfl_xor(rs, 16, 64);
    rs += __shfl_xor(rs, 32, 64);
    l = fmaf(l, scv, rs);
    // P -> per-wave pbuf in A-frag layout (wave-local, no barrier)
#pragma unroll
    for (int t = 0; t < 4; ++t) {
      unsigned plo = pk2(s4[t][0], s4[t][1]);
      unsigned phi = pk2(s4[t][2], s4[t][3]);
      *(uint2*)(&pbuf[w][li][t * 16 + kb * 4]) = make_uint2(plo, phi);
    }
    short8v pa0 = *(const short8v*)(&pbuf[w][li][kb * 8]);
    short8v pa1 = *(const short8v*)(&pbuf[w][li][32 + kb * 8]);
    // PV straight from global Vt (L1/L2 hit)
#pragma unroll
    for (int dt = 0; dt < 4; ++dt) {
      short8v vf0 = *(const short8v*)(Vl + dt * 8192 + ch * 64);
      short8v vf1 = *(const short8v*)(Vl + dt * 8192 + ch * 64 + 32);
      o[dt] = MFMA_BF16(pa0, vf0, o[dt], 0, 0, 0);
      o[dt] = MFMA_BF16(pa1, vf1, o[dt], 0, 0, 0);
    }
  }
  float iv = 1.0f / l;
  float iv4[4];
#pragma unroll
  for (int r = 0; r < 4; ++r) iv4[r] = __shfl(iv, ((lane >> 4) << 2) + r, 16);
  int op[4];
#pragma unroll
  for (int r = 0; r < 4; ++r)
    op[r] = perm[n * 512 + p0 + kb * 4 + r];
#pragma unroll
  for (int dt = 0; dt < 4; ++dt)
#pragma unroll
    for (int r = 0; r < 4; ++r)
      O[(size_t)op[r] * 512 + h * 64 + dt * 16 + li] = f2bf(o[dt][r] * iv4[r]);
}

// ---------------- proj GEMM (bf16), T2-swizzled LDS ----------------

__global__ __launch_bounds__(256) void proj_gemm(const ushort_t* __restrict__ A,
    const ushort_t* __restrict__ W, const float* __restrict__ bias,
    float* __restrict__ out)
{
  __shared__ __align__(16) ushort_t la[128 * 64];
  __shared__ __align__(16) ushort_t lb[128 * 64];
  const int bid = blockIdx.x;                 // 2048 = 4 x 512, XCD-chunked
  const int swz = (bid & 7) * 256 + (bid >> 3);
  const int bx = swz & 3, by = swz >> 2;
  const int rowBase = by * 128, colBase = bx * 128;
  const int tid = threadIdx.x, lane = tid & 63, w = tid >> 6;
  const int wr = w >> 1, wc = w & 1;
  const int li = lane & 15, kb = lane >> 4;
  const int lr = lane >> 3;
  const int lcs = (((lane & 7) ^ lr) << 3);
  f32x4 acc[4][4] = {};
  for (int kt = 0; kt < 8; ++kt) {
#pragma unroll
    for (int i = 0; i < 4; ++i) {
      int c = w * 4 + i;
      async16(la + c * 512, A + (size_t)(rowBase + c * 8 + lr) * 512 + kt * 64 + lcs);
      async16(lb + c * 512, W + (size_t)(colBase + c * 8 + lr) * 512 + kt * 64 + lcs);
    }
    __syncthreads();
    short8v af[2][4], bfr[2][4];
#pragma unroll
    for (int kk = 0; kk < 2; ++kk)
#pragma unroll
      for (int t = 0; t < 4; ++t) {
        int sl = ((kk * 4 + kb) ^ (li & 7)) << 3;
        af[kk][t]  = *(const short8v*)(la + (wr * 64 + t * 16 + li) * 64 + sl);
        bfr[kk][t] = *(const short8v*)(lb + (wc * 64 + t * 16 + li) * 64 + sl);
      }
#pragma unroll
    for (int kk = 0; kk < 2; ++kk)
#pragma unroll
      for (int i = 0; i < 4; ++i)
#pragma unroll
        for (int j = 0; j < 4; ++j)
          acc[i][j] = MFMA_BF16(af[kk][i], bfr[kk][j], acc[i][j], 0, 0, 0);
    __syncthreads();
  }
#pragma unroll
  for (int i = 0; i < 4; ++i)
#pragma unroll
    for (int j = 0; j < 4; ++j) {
      int col = colBase + wc * 64 + j * 16 + li;
      float bv = bias[col];
#pragma unroll
      for (int r = 0; r < 4; ++r) {
        int m = rowBase + wr * 64 + i * 16 + kb * 4 + r;
        out[(size_t)m * 512 + col] = acc[i][j][r] + bv;
      }
    }
}

// ---------------- launch ----------------

extern "C" void kernel_launch(void* const* d_in, const int* in_sizes, int n_in,
                              void* d_out, int out_size, void* d_ws, size_t ws_size,
                              hipStream_t stream) {
  (void)in_sizes; (void)n_in; (void)out_size; (void)ws_size;
  const float* feats      = (const float*)d_in[0];
  const int* codes        = (const int*)d_in[1];   // int64 in reference, delivered as int32
  const float* Wqkv       = (const float*)d_in[2];
  const float* bqkv       = (const float*)d_in[3];
  const float* Wproj      = (const float*)d_in[4];
  const float* bproj      = (const float*)d_in[5];
  float* out = (float*)d_out;

  char* ws = (char*)d_ws;
  int* perm = (int*)(ws);
  u64* keys = (u64*)(ws + 262144);
  ushort_t* Abf     = (ushort_t*)(ws + 1048576);                       // 64 MB
  ushort_t* att     = Abf;                                             // reuse
  ushort_t* Wqkvbf  = (ushort_t*)(ws + 1048576 + 67108864);            // 1.5 MB
  ushort_t* Wprojbf = (ushort_t*)(ws + 1048576 + 67108864 + 1572864);  // 0.5 MB
  ushort_t* Qb      = (ushort_t*)(ws + 1048576 + 67108864 + 2097152);
  ushort_t* Kb      = Qb + 33554432ull;
  ushort_t* Vt      = Kb + 33554432ull;

  sort_chunk<<<16, 512, 0, stream>>>(codes, keys);
  sort_gpass<<<256, 256, 0, stream>>>(keys, 8192, 4096);
  sort_finish<<<16, 512, 0, stream>>>(keys, 8192);
  sort_gpass<<<256, 256, 0, stream>>>(keys, 16384, 8192);
  sort_gpass<<<256, 256, 0, stream>>>(keys, 16384, 4096);
  sort_finish<<<16, 512, 0, stream>>>(keys, 16384);
  write_perm<<<256, 256, 0, stream>>>(keys, perm);

  gather_bf16<<<8192, 256, 0, stream>>>(feats, perm, Abf);
  convert_bf16<<<384, 256, 0, stream>>>(Wqkv, Wqkvbf);
  convert_bf16<<<128, 256, 0, stream>>>(Wproj, Wprojbf);

  qkv_gemm<<<6144, 256, 0, stream>>>(Abf, Wqkvbf, bqkv, Qb, Kb, Vt);
  attn_kernel<<<8192, 256, 0, stream>>>(Qb, Kb, Vt, perm, att);
  proj_gemm<<<2048, 256, 0, stream>>>(att, Wprojbf, bproj, out);
}

// Round 9
// 481.181 us; speedup vs baseline: 1.6795x; 1.6795x over previous
//
#include <hip/hip_runtime.h>
#include <hip/hip_bf16.h>

// PTV3 attention: sort -> gather+bf16 prepass -> bf16 QKV GEMM -> flash MHA
// (online softmax, swapped QK^T, dbuf LDS K/V + register prestage (T14),
// defer-max (T13), scattered write) -> bf16 proj GEMM.
// GEMMs: m97 + T2 swizzle + coalesced Vt epilogue.

typedef unsigned long long u64;
typedef unsigned short ushort_t;
typedef __attribute__((ext_vector_type(8))) short short8v;
typedef __attribute__((ext_vector_type(4))) float f32x4;

#define MFMA_BF16 __builtin_amdgcn_mfma_f32_16x16x32_bf16

__device__ __forceinline__ unsigned short f2bf(float f) {
  union { float f; unsigned u; } v; v.f = f;
  return (unsigned short)((v.u + 0x7FFFu + ((v.u >> 16) & 1u)) >> 16);
}

__device__ __forceinline__ unsigned pk2(float a, float b) {
  __hip_bfloat162 h = __float22bfloat162_rn(float2{a, b});
  unsigned u; __builtin_memcpy(&u, &h, 4); return u;
}

// async global->LDS, 16B per lane; LDS dest = wave-uniform base + lane*16
__device__ __forceinline__ void async16(ushort_t* lds, const ushort_t* g) {
  __builtin_amdgcn_global_load_lds(
      (const __attribute__((address_space(1))) unsigned int*)g,
      (__attribute__((address_space(3))) unsigned int*)lds, 16, 0, 0);
}

// ---------------- stable sort of (code, idx) per 16384-group ----------------

__global__ __launch_bounds__(512) void sort_chunk(const int* __restrict__ codes,
                                                  u64* __restrict__ keys) {
  __shared__ u64 sk[4096];
  const int base = blockIdx.x * 4096;
  for (int t = threadIdx.x; t < 4096; t += 512) {
    int e = base + t;
    sk[t] = (((u64)(unsigned)codes[e]) << 14) | (u64)(e & 16383);
  }
  __syncthreads();
  for (int k = 2; k <= 4096; k <<= 1) {
    for (int j = k >> 1; j > 0; j >>= 1) {
      for (int t = threadIdx.x; t < 4096; t += 512) {
        int jx = t ^ j;
        if (jx > t) {
          bool up = (((base + t) & 16383 & k) == 0);
          u64 a = sk[t], b = sk[jx];
          if ((a > b) == up) { sk[t] = b; sk[jx] = a; }
        }
      }
      __syncthreads();
    }
  }
  for (int t = threadIdx.x; t < 4096; t += 512) keys[base + t] = sk[t];
}

__global__ __launch_bounds__(256) void sort_gpass(u64* __restrict__ keys, int k, int j) {
  int t = blockIdx.x * 256 + threadIdx.x;
  int jx = t ^ j;
  if (jx > t) {
    bool up = ((t & 16383 & k) == 0);
    u64 a = keys[t], b = keys[jx];
    if ((a > b) == up) { keys[t] = b; keys[jx] = a; }
  }
}

__global__ __launch_bounds__(512) void sort_finish(u64* __restrict__ keys, int k) {
  __shared__ u64 sk[4096];
  const int base = blockIdx.x * 4096;
  for (int t = threadIdx.x; t < 4096; t += 512) sk[t] = keys[base + t];
  __syncthreads();
  for (int j = 2048; j > 0; j >>= 1) {
    for (int t = threadIdx.x; t < 4096; t += 512) {
      int jx = t ^ j;
      if (jx > t) {
        bool up = (((base + t) & 16383 & k) == 0);
        u64 a = sk[t], b = sk[jx];
        if ((a > b) == up) { sk[t] = b; sk[jx] = a; }
      }
    }
    __syncthreads();
  }
  for (int t = threadIdx.x; t < 4096; t += 512) keys[base + t] = sk[t];
}

__global__ __launch_bounds__(256) void write_perm(const u64* __restrict__ keys,
                                                  int* __restrict__ perm) {
  int t = blockIdx.x * 256 + threadIdx.x;
  int g = t >> 14;
  int a = (int)(keys[t] & 16383);
  perm[t] = (g << 14) | a;        // perm[sorted pos] = original row
}

// ---------------- prepass: Abf[m][k] = bf16(feats[perm[m]][k]) ----------------

__global__ __launch_bounds__(256) void gather_bf16(const float* __restrict__ feats,
    const int* __restrict__ perm, ushort_t* __restrict__ A) {
  int t = blockIdx.x * 256 + threadIdx.x;
  int m = t >> 5;
  int off = (t & 31) << 4;
  const float* src = feats + (size_t)perm[m] * 512 + off;
  float4 a = ((const float4*)src)[0];
  float4 b = ((const float4*)src)[1];
  float4 c = ((const float4*)src)[2];
  float4 d = ((const float4*)src)[3];
  short8v lo = { (short)f2bf(a.x), (short)f2bf(a.y), (short)f2bf(a.z), (short)f2bf(a.w),
                 (short)f2bf(b.x), (short)f2bf(b.y), (short)f2bf(b.z), (short)f2bf(b.w) };
  short8v hi = { (short)f2bf(c.x), (short)f2bf(c.y), (short)f2bf(c.z), (short)f2bf(c.w),
                 (short)f2bf(d.x), (short)f2bf(d.y), (short)f2bf(d.z), (short)f2bf(d.w) };
  ushort_t* dst = A + (size_t)m * 512 + off;
  *(short8v*)(dst) = lo;
  *(short8v*)(dst + 8) = hi;
}

__global__ __launch_bounds__(256) void convert_bf16(const float* __restrict__ src,
                                                    ushort_t* __restrict__ dst) {
  int t = blockIdx.x * 256 + threadIdx.x;
  const float* s = src + (size_t)t * 8;
  float4 a = ((const float4*)s)[0];
  float4 b = ((const float4*)s)[1];
  short8v v = { (short)f2bf(a.x), (short)f2bf(a.y), (short)f2bf(a.z), (short)f2bf(a.w),
                (short)f2bf(b.x), (short)f2bf(b.y), (short)f2bf(b.z), (short)f2bf(b.w) };
  *(short8v*)(dst + (size_t)t * 8) = v;
}

// ---------------- QKV GEMM (bf16), T2-swizzled LDS ----------------
// LDS content: lds(row, slot16) = g(row, slot16 ^ (row&7)); involution on both sides.

__global__ __launch_bounds__(256) void qkv_gemm(const ushort_t* __restrict__ A,
    const ushort_t* __restrict__ W, const float* __restrict__ bias,
    ushort_t* __restrict__ Q, ushort_t* __restrict__ Ko, ushort_t* __restrict__ Vt)
{
  __shared__ __align__(16) ushort_t la[128 * 64];
  __shared__ __align__(16) ushort_t lb[128 * 64];
  const int bid = blockIdx.x;                 // 6144 = 12 x 512, XCD-chunked
  const int swz = (bid & 7) * 768 + (bid >> 3);
  const int bx = swz % 12, by = swz / 12;
  const int rowBase = by * 128, colBase = bx * 128;
  const int tid = threadIdx.x, lane = tid & 63, w = tid >> 6;
  const int wr = w >> 1, wc = w & 1;
  const int li = lane & 15, kb = lane >> 4;
  const int lr = lane >> 3;
  const int lcs = (((lane & 7) ^ lr) << 3);   // pre-swizzled source col (elems)
  f32x4 acc[4][4] = {};
  for (int kt = 0; kt < 8; ++kt) {
#pragma unroll
    for (int i = 0; i < 4; ++i) {
      int c = w * 4 + i;
      async16(la + c * 512, A + (size_t)(rowBase + c * 8 + lr) * 512 + kt * 64 + lcs);
      async16(lb + c * 512, W + (size_t)(colBase + c * 8 + lr) * 512 + kt * 64 + lcs);
    }
    __syncthreads();
    short8v af[2][4], bfr[2][4];
#pragma unroll
    for (int kk = 0; kk < 2; ++kk)
#pragma unroll
      for (int t = 0; t < 4; ++t) {
        int sl = ((kk * 4 + kb) ^ (li & 7)) << 3;   // swizzled read slot
        af[kk][t]  = *(const short8v*)(la + (wr * 64 + t * 16 + li) * 64 + sl);
        bfr[kk][t] = *(const short8v*)(lb + (wc * 64 + t * 16 + li) * 64 + sl);
      }
#pragma unroll
    for (int kk = 0; kk < 2; ++kk)
#pragma unroll
      for (int i = 0; i < 4; ++i)
#pragma unroll
        for (int j = 0; j < 4; ++j)
          acc[i][j] = MFMA_BF16(af[kk][i], bfr[kk][j], acc[i][j], 0, 0, 0);
    __syncthreads();
  }
  const int c0 = colBase + wc * 64;           // wave's first global col
  if (c0 >= 1024) {
    // ---- V block: transpose 64x64 subtile via private LDS, store p-contiguous ----
    ushort_t* tw = (w < 2) ? (la + w * 4096) : (lb + (w - 2) * 4096);
    char* twb = (char*)tw;
#pragma unroll
    for (int j = 0; j < 4; ++j) {
      int dloc = j * 16 + li;
      float bv = bias[c0 + dloc];
#pragma unroll
      for (int i = 0; i < 4; ++i) {
        unsigned u0 = pk2(acc[i][j][0] + bv, acc[i][j][1] + bv);
        unsigned u1 = pk2(acc[i][j][2] + bv, acc[i][j][3] + bv);
        int s = i * 2 + (kb >> 1);
        int byte = dloc * 128 + ((s ^ (dloc & 7)) << 4) + ((kb & 1) << 3);
        *(uint2*)(twb + byte) = make_uint2(u0, u1);
      }
    }
    const int h = (c0 - 1024) >> 6;
    const size_t nh = (size_t)((rowBase >> 9) * 8 + h);
    const int pbase = ((rowBase + wr * 64) & 511) + ((lane & 7) << 3);
    ushort_t* vb = Vt + nh * 32768 + pbase;
#pragma unroll
    for (int ps = 0; ps < 8; ++ps) {
      int dloc = ps * 8 + (lane >> 3);
      int byte = dloc * 128 + ((((lane & 7)) ^ (dloc & 7)) << 4);
      short8v vv = *(const short8v*)(twb + byte);
      *(short8v*)(vb + dloc * 512) = vv;
    }
  } else {
    // ---- Q/K block: original store path ----
#pragma unroll
    for (int j = 0; j < 4; ++j) {
      int colb = c0 + j * 16;
      int col = colb + li;
      float bv = bias[col];
      int c3 = colb >> 9;
      int h = (col >> 6) & 7;
      int d = col & 63;
#pragma unroll
      for (int i = 0; i < 4; ++i) {
        int m0 = rowBase + wr * 64 + i * 16 + kb * 4;
#pragma unroll
        for (int r = 0; r < 4; ++r) {
          int m = m0 + r;
          int n = m >> 9, p = m & 511;
          unsigned short bv16 = f2bf(acc[i][j][r] + bv);
          size_t nh = (size_t)(n * 8 + h);
          if (c3 == 0) Q [(nh * 512 + p) * 64 + d] = bv16;
          else         Ko[(nh * 512 + p) * 64 + d] = bv16;
        }
      }
    }
  }
}

// ---------------- flash attention: dbuf LDS K/V, 1 barrier/chunk ----------------
// wave = 16 q-rows. Swapped QK^T (S[k][q=li] lane-local k-reduce + 2 shfl).
// T14: next chunk's K/V loaded to regs BEFORE compute, written to the alternate
// LDS buffer AFTER compute -> HBM/L2 latency hidden, one barrier per chunk.
// T13 defer-max: skip O-rescale while max stable (P <= e^2, bf16-safe).

__global__ __launch_bounds__(256) void attn_kernel(const ushort_t* __restrict__ Q,
    const ushort_t* __restrict__ K, const ushort_t* __restrict__ Vt,
    const int* __restrict__ perm, ushort_t* __restrict__ O)
{
  __shared__ __align__(16) ushort_t kbuf[2][64][72];
  __shared__ __align__(16) ushort_t vbuf[2][64][72];
  __shared__ __align__(16) ushort_t pbuf[4][16][72];
  const int b = blockIdx.x;
  const int qc = (b >> 3) & 7;
  const int nh = ((b >> 6) << 3) | (b & 7);
  const int n = nh >> 3, h = nh & 7;
  const int tid = threadIdx.x, w = tid >> 6, lane = tid & 63;
  const int li = lane & 15, kb = lane >> 4;
  const ushort_t* Qb = Q + (size_t)nh * (512 * 64);
  const ushort_t* Kb = K + (size_t)nh * (512 * 64);
  const ushort_t* Vb = Vt + (size_t)nh * (64 * 512);
  const int p0 = qc * 64 + w * 16;
  const int sgr = tid >> 3, sgc = (tid & 7) << 3;   // stage row (0..31), col

  short8v qf0 = *(const short8v*)(Qb + (size_t)(p0 + li) * 64 + kb * 8);
  short8v qf1 = *(const short8v*)(Qb + (size_t)(p0 + li) * 64 + 32 + kb * 8);

  f32x4 o[4] = {};
  float m = -1e30f, l = 0.f;
  const float cs = 0.125f * 1.44269504088896340736f;  // scale * log2(e)

  short8v kr0, kr1, vr0, vr1;
  // prologue: stage chunk 0
  kr0 = *(const short8v*)(Kb + (size_t)sgr * 64 + sgc);
  kr1 = *(const short8v*)(Kb + (size_t)(32 + sgr) * 64 + sgc);
  vr0 = *(const short8v*)(Vb + (size_t)sgr * 512 + sgc);
  vr1 = *(const short8v*)(Vb + (size_t)(32 + sgr) * 512 + sgc);
  *(short8v*)(&kbuf[0][sgr][sgc]) = kr0;
  *(short8v*)(&kbuf[0][32 + sgr][sgc]) = kr1;
  *(short8v*)(&vbuf[0][sgr][sgc]) = vr0;
  *(short8v*)(&vbuf[0][32 + sgr][sgc]) = vr1;
  __syncthreads();

#pragma unroll
  for (int ch = 0; ch < 8; ++ch) {
    const int cur = ch & 1;
    // T14: issue next chunk's loads now; vmcnt drains before the LDS write below
    if (ch < 7) {
      kr0 = *(const short8v*)(Kb + (size_t)((ch + 1) * 64 + sgr) * 64 + sgc);
      kr1 = *(const short8v*)(Kb + (size_t)((ch + 1) * 64 + 32 + sgr) * 64 + sgc);
      vr0 = *(const short8v*)(Vb + (size_t)sgr * 512 + (ch + 1) * 64 + sgc);
      vr1 = *(const short8v*)(Vb + (size_t)(32 + sgr) * 512 + (ch + 1) * 64 + sgc);
    }
    // QK^T: S[k=16t+4kb+r][q=li]
    f32x4 s4[4];
#pragma unroll
    for (int t = 0; t < 4; ++t) {
      short8v kf0 = *(const short8v*)(&kbuf[cur][t * 16 + li][kb * 8]);
      short8v kf1 = *(const short8v*)(&kbuf[cur][t * 16 + li][32 + kb * 8]);
      f32x4 z = {0.f, 0.f, 0.f, 0.f};
      z = MFMA_BF16(kf0, qf0, z, 0, 0, 0);
      z = MFMA_BF16(kf1, qf1, z, 0, 0, 0);
      s4[t] = z;
    }
    // chunk max per q (max3-friendly tree) + cross-kb reduce
    float ta = fmaxf(fmaxf(s4[0][0], s4[0][1]), s4[0][2]);
    float tb = fmaxf(fmaxf(s4[0][3], s4[1][0]), s4[1][1]);
    float tc = fmaxf(fmaxf(s4[1][2], s4[1][3]), s4[2][0]);
    float td = fmaxf(fmaxf(s4[2][1], s4[2][2]), s4[2][3]);
    float te = fmaxf(fmaxf(s4[3][0], s4[3][1]), s4[3][2]);
    float pm = fmaxf(fmaxf(fmaxf(ta, tb), fmaxf(tc, td)), fmaxf(te, s4[3][3]));
    pm = fmaxf(pm, __shfl_xor(pm, 16, 64));
    pm = fmaxf(pm, __shfl_xor(pm, 32, 64));
    // T13 defer-max
    float scv = 1.0f;
    if (!__all(pm <= m + 16.0f)) {
      float mn = fmaxf(m, pm);
      scv = exp2f((m - mn) * cs);
      m = mn;
      float sr4[4];
#pragma unroll
      for (int r = 0; r < 4; ++r) sr4[r] = __shfl(scv, (kb << 2) + r, 16);
#pragma unroll
      for (int dt = 0; dt < 4; ++dt)
#pragma unroll
        for (int r = 0; r < 4; ++r) o[dt][r] *= sr4[r];
    }
    const float nm = -m * cs;
    float rsa = 0.f, rsb = 0.f;
#pragma unroll
    for (int t = 0; t < 4; ++t)
#pragma unroll
      for (int r = 0; r < 4; ++r) {
        float ev = exp2f(fmaf(s4[t][r], cs, nm));
        s4[t][r] = ev;
        if (r & 1) rsb += ev; else rsa += ev;
      }
    float rs = rsa + rsb;
    rs += __shfl_xor(rs, 16, 64);
    rs += __shfl_xor(rs, 32, 64);
    l = fmaf(l, scv, rs);
    // P -> per-wave pbuf in A-frag layout (wave-local, no barrier)
#pragma unroll
    for (int t = 0; t < 4; ++t) {
      unsigned plo = pk2(s4[t][0], s4[t][1]);
      unsigned phi = pk2(s4[t][2], s4[t][3]);
      *(uint2*)(&pbuf[w][li][t * 16 + kb * 4]) = make_uint2(plo, phi);
    }
    short8v pa0 = *(const short8v*)(&pbuf[w][li][kb * 8]);
    short8v pa1 = *(const short8v*)(&pbuf[w][li][32 + kb * 8]);
    // PV from LDS
#pragma unroll
    for (int dt = 0; dt < 4; ++dt) {
      short8v vf0 = *(const short8v*)(&vbuf[cur][dt * 16 + li][kb * 8]);
      short8v vf1 = *(const short8v*)(&vbuf[cur][dt * 16 + li][32 + kb * 8]);
      o[dt] = MFMA_BF16(pa0, vf0, o[dt], 0, 0, 0);
      o[dt] = MFMA_BF16(pa1, vf1, o[dt], 0, 0, 0);
    }
    // write next chunk to the alternate buffer; single barrier per chunk
    if (ch < 7) {
      *(short8v*)(&kbuf[cur ^ 1][sgr][sgc]) = kr0;
      *(short8v*)(&kbuf[cur ^ 1][32 + sgr][sgc]) = kr1;
      *(short8v*)(&vbuf[cur ^ 1][sgr][sgc]) = vr0;
      *(short8v*)(&vbuf[cur ^ 1][32 + sgr][sgc]) = vr1;
    }
    __syncthreads();
  }
  float iv = 1.0f / l;
  float iv4[4];
#pragma unroll
  for (int r = 0; r < 4; ++r) iv4[r] = __shfl(iv, (kb << 2) + r, 16);
  int op[4];
#pragma unroll
  for (int r = 0; r < 4; ++r)
    op[r] = perm[n * 512 + p0 + kb * 4 + r];
#pragma unroll
  for (int dt = 0; dt < 4; ++dt)
#pragma unroll
    for (int r = 0; r < 4; ++r)
      O[(size_t)op[r] * 512 + h * 64 + dt * 16 + li] = f2bf(o[dt][r] * iv4[r]);
}

// ---------------- proj GEMM (bf16), T2-swizzled LDS ----------------

__global__ __launch_bounds__(256) void proj_gemm(const ushort_t* __restrict__ A,
    const ushort_t* __restrict__ W, const float* __restrict__ bias,
    float* __restrict__ out)
{
  __shared__ __align__(16) ushort_t la[128 * 64];
  __shared__ __align__(16) ushort_t lb[128 * 64];
  const int bid = blockIdx.x;                 // 2048 = 4 x 512, XCD-chunked
  const int swz = (bid & 7) * 256 + (bid >> 3);
  const int bx = swz & 3, by = swz >> 2;
  const int rowBase = by * 128, colBase = bx * 128;
  const int tid = threadIdx.x, lane = tid & 63, w = tid >> 6;
  const int wr = w >> 1, wc = w & 1;
  const int li = lane & 15, kb = lane >> 4;
  const int lr = lane >> 3;
  const int lcs = (((lane & 7) ^ lr) << 3);
  f32x4 acc[4][4] = {};
  for (int kt = 0; kt < 8; ++kt) {
#pragma unroll
    for (int i = 0; i < 4; ++i) {
      int c = w * 4 + i;
      async16(la + c * 512, A + (size_t)(rowBase + c * 8 + lr) * 512 + kt * 64 + lcs);
      async16(lb + c * 512, W + (size_t)(colBase + c * 8 + lr) * 512 + kt * 64 + lcs);
    }
    __syncthreads();
    short8v af[2][4], bfr[2][4];
#pragma unroll
    for (int kk = 0; kk < 2; ++kk)
#pragma unroll
      for (int t = 0; t < 4; ++t) {
        int sl = ((kk * 4 + kb) ^ (li & 7)) << 3;
        af[kk][t]  = *(const short8v*)(la + (wr * 64 + t * 16 + li) * 64 + sl);
        bfr[kk][t] = *(const short8v*)(lb + (wc * 64 + t * 16 + li) * 64 + sl);
      }
#pragma unroll
    for (int kk = 0; kk < 2; ++kk)
#pragma unroll
      for (int i = 0; i < 4; ++i)
#pragma unroll
        for (int j = 0; j < 4; ++j)
          acc[i][j] = MFMA_BF16(af[kk][i], bfr[kk][j], acc[i][j], 0, 0, 0);
    __syncthreads();
  }
#pragma unroll
  for (int i = 0; i < 4; ++i)
#pragma unroll
    for (int j = 0; j < 4; ++j) {
      int col = colBase + wc * 64 + j * 16 + li;
      float bv = bias[col];
#pragma unroll
      for (int r = 0; r < 4; ++r) {
        int m = rowBase + wr * 64 + i * 16 + kb * 4 + r;
        out[(size_t)m * 512 + col] = acc[i][j][r] + bv;
      }
    }
}

// ---------------- launch ----------------

extern "C" void kernel_launch(void* const* d_in, const int* in_sizes, int n_in,
                              void* d_out, int out_size, void* d_ws, size_t ws_size,
                              hipStream_t stream) {
  (void)in_sizes; (void)n_in; (void)out_size; (void)ws_size;
  const float* feats      = (const float*)d_in[0];
  const int* codes        = (const int*)d_in[1];   // int64 in reference, delivered as int32
  const float* Wqkv       = (const float*)d_in[2];
  const float* bqkv       = (const float*)d_in[3];
  const float* Wproj      = (const float*)d_in[4];
  const float* bproj      = (const float*)d_in[5];
  float* out = (float*)d_out;

  char* ws = (char*)d_ws;
  int* perm = (int*)(ws);
  u64* keys = (u64*)(ws + 262144);
  ushort_t* Abf     = (ushort_t*)(ws + 1048576);                       // 64 MB
  ushort_t* att     = Abf;                                             // reuse
  ushort_t* Wqkvbf  = (ushort_t*)(ws + 1048576 + 67108864);            // 1.5 MB
  ushort_t* Wprojbf = (ushort_t*)(ws + 1048576 + 67108864 + 1572864);  // 0.5 MB
  ushort_t* Qb      = (ushort_t*)(ws + 1048576 + 67108864 + 2097152);
  ushort_t* Kb      = Qb + 33554432ull;
  ushort_t* Vt      = Kb + 33554432ull;

  sort_chunk<<<16, 512, 0, stream>>>(codes, keys);
  sort_gpass<<<256, 256, 0, stream>>>(keys, 8192, 4096);
  sort_finish<<<16, 512, 0, stream>>>(keys, 8192);
  sort_gpass<<<256, 256, 0, stream>>>(keys, 16384, 8192);
  sort_gpass<<<256, 256, 0, stream>>>(keys, 16384, 4096);
  sort_finish<<<16, 512, 0, stream>>>(keys, 16384);
  write_perm<<<256, 256, 0, stream>>>(keys, perm);

  gather_bf16<<<8192, 256, 0, stream>>>(feats, perm, Abf);
  convert_bf16<<<384, 256, 0, stream>>>(Wqkv, Wqkvbf);
  convert_bf16<<<128, 256, 0, stream>>>(Wproj, Wprojbf);

  qkv_gemm<<<6144, 256, 0, stream>>>(Abf, Wqkvbf, bqkv, Qb, Kb, Vt);
  attn_kernel<<<8192, 256, 0, stream>>>(Qb, Kb, Vt, perm, att);
  proj_gemm<<<2048, 256, 0, stream>>>(att, Wprojbf, bproj, out);
}

// Round 10
// 470.695 us; speedup vs baseline: 1.7169x; 1.0223x over previous
//
#include <hip/hip_runtime.h>
#include <hip/hip_bf16.h>

// PTV3 attention: sort -> gather+bf16 prepass -> bf16 QKV GEMM -> flash MHA
// (2 q-tiles/wave, gload_lds K/V dbuf w/ T2 XOR swizzle, 1 barrier/chunk,
// defer-max, scattered write) -> bf16 proj GEMM.
// GEMMs: m97 + T2 swizzle + coalesced Vt epilogue.

typedef unsigned long long u64;
typedef unsigned short ushort_t;
typedef __attribute__((ext_vector_type(8))) short short8v;
typedef __attribute__((ext_vector_type(4))) float f32x4;

#define MFMA_BF16 __builtin_amdgcn_mfma_f32_16x16x32_bf16

__device__ __forceinline__ unsigned short f2bf(float f) {
  union { float f; unsigned u; } v; v.f = f;
  return (unsigned short)((v.u + 0x7FFFu + ((v.u >> 16) & 1u)) >> 16);
}

__device__ __forceinline__ unsigned pk2(float a, float b) {
  __hip_bfloat162 h = __float22bfloat162_rn(float2{a, b});
  unsigned u; __builtin_memcpy(&u, &h, 4); return u;
}

// async global->LDS, 16B per lane; LDS dest = wave-uniform base + lane*16
__device__ __forceinline__ void async16(ushort_t* lds, const ushort_t* g) {
  __builtin_amdgcn_global_load_lds(
      (const __attribute__((address_space(1))) unsigned int*)g,
      (__attribute__((address_space(3))) unsigned int*)lds, 16, 0, 0);
}

// ---------------- stable sort of (code, idx) per 16384-group ----------------

__global__ __launch_bounds__(512) void sort_chunk(const int* __restrict__ codes,
                                                  u64* __restrict__ keys) {
  __shared__ u64 sk[4096];
  const int base = blockIdx.x * 4096;
  for (int t = threadIdx.x; t < 4096; t += 512) {
    int e = base + t;
    sk[t] = (((u64)(unsigned)codes[e]) << 14) | (u64)(e & 16383);
  }
  __syncthreads();
  for (int k = 2; k <= 4096; k <<= 1) {
    for (int j = k >> 1; j > 0; j >>= 1) {
      for (int t = threadIdx.x; t < 4096; t += 512) {
        int jx = t ^ j;
        if (jx > t) {
          bool up = (((base + t) & 16383 & k) == 0);
          u64 a = sk[t], b = sk[jx];
          if ((a > b) == up) { sk[t] = b; sk[jx] = a; }
        }
      }
      __syncthreads();
    }
  }
  for (int t = threadIdx.x; t < 4096; t += 512) keys[base + t] = sk[t];
}

__global__ __launch_bounds__(256) void sort_gpass(u64* __restrict__ keys, int k, int j) {
  int t = blockIdx.x * 256 + threadIdx.x;
  int jx = t ^ j;
  if (jx > t) {
    bool up = ((t & 16383 & k) == 0);
    u64 a = keys[t], b = keys[jx];
    if ((a > b) == up) { keys[t] = b; keys[jx] = a; }
  }
}

__global__ __launch_bounds__(512) void sort_finish(u64* __restrict__ keys, int k) {
  __shared__ u64 sk[4096];
  const int base = blockIdx.x * 4096;
  for (int t = threadIdx.x; t < 4096; t += 512) sk[t] = keys[base + t];
  __syncthreads();
  for (int j = 2048; j > 0; j >>= 1) {
    for (int t = threadIdx.x; t < 4096; t += 512) {
      int jx = t ^ j;
      if (jx > t) {
        bool up = (((base + t) & 16383 & k) == 0);
        u64 a = sk[t], b = sk[jx];
        if ((a > b) == up) { sk[t] = b; sk[jx] = a; }
      }
    }
    __syncthreads();
  }
  for (int t = threadIdx.x; t < 4096; t += 512) keys[base + t] = sk[t];
}

__global__ __launch_bounds__(256) void write_perm(const u64* __restrict__ keys,
                                                  int* __restrict__ perm) {
  int t = blockIdx.x * 256 + threadIdx.x;
  int g = t >> 14;
  int a = (int)(keys[t] & 16383);
  perm[t] = (g << 14) | a;        // perm[sorted pos] = original row
}

// ---------------- prepass: Abf[m][k] = bf16(feats[perm[m]][k]) ----------------

__global__ __launch_bounds__(256) void gather_bf16(const float* __restrict__ feats,
    const int* __restrict__ perm, ushort_t* __restrict__ A) {
  int t = blockIdx.x * 256 + threadIdx.x;
  int m = t >> 5;
  int off = (t & 31) << 4;
  const float* src = feats + (size_t)perm[m] * 512 + off;
  float4 a = ((const float4*)src)[0];
  float4 b = ((const float4*)src)[1];
  float4 c = ((const float4*)src)[2];
  float4 d = ((const float4*)src)[3];
  short8v lo = { (short)f2bf(a.x), (short)f2bf(a.y), (short)f2bf(a.z), (short)f2bf(a.w),
                 (short)f2bf(b.x), (short)f2bf(b.y), (short)f2bf(b.z), (short)f2bf(b.w) };
  short8v hi = { (short)f2bf(c.x), (short)f2bf(c.y), (short)f2bf(c.z), (short)f2bf(c.w),
                 (short)f2bf(d.x), (short)f2bf(d.y), (short)f2bf(d.z), (short)f2bf(d.w) };
  ushort_t* dst = A + (size_t)m * 512 + off;
  *(short8v*)(dst) = lo;
  *(short8v*)(dst + 8) = hi;
}

__global__ __launch_bounds__(256) void convert_bf16(const float* __restrict__ src,
                                                    ushort_t* __restrict__ dst) {
  int t = blockIdx.x * 256 + threadIdx.x;
  const float* s = src + (size_t)t * 8;
  float4 a = ((const float4*)s)[0];
  float4 b = ((const float4*)s)[1];
  short8v v = { (short)f2bf(a.x), (short)f2bf(a.y), (short)f2bf(a.z), (short)f2bf(a.w),
                (short)f2bf(b.x), (short)f2bf(b.y), (short)f2bf(b.z), (short)f2bf(b.w) };
  *(short8v*)(dst + (size_t)t * 8) = v;
}

// ---------------- QKV GEMM (bf16), T2-swizzled LDS ----------------

__global__ __launch_bounds__(256) void qkv_gemm(const ushort_t* __restrict__ A,
    const ushort_t* __restrict__ W, const float* __restrict__ bias,
    ushort_t* __restrict__ Q, ushort_t* __restrict__ Ko, ushort_t* __restrict__ Vt)
{
  __shared__ __align__(16) ushort_t la[128 * 64];
  __shared__ __align__(16) ushort_t lb[128 * 64];
  const int bid = blockIdx.x;                 // 6144 = 12 x 512, XCD-chunked
  const int swz = (bid & 7) * 768 + (bid >> 3);
  const int bx = swz % 12, by = swz / 12;
  const int rowBase = by * 128, colBase = bx * 128;
  const int tid = threadIdx.x, lane = tid & 63, w = tid >> 6;
  const int wr = w >> 1, wc = w & 1;
  const int li = lane & 15, kb = lane >> 4;
  const int lr = lane >> 3;
  const int lcs = (((lane & 7) ^ lr) << 3);   // pre-swizzled source col (elems)
  f32x4 acc[4][4] = {};
  for (int kt = 0; kt < 8; ++kt) {
#pragma unroll
    for (int i = 0; i < 4; ++i) {
      int c = w * 4 + i;
      async16(la + c * 512, A + (size_t)(rowBase + c * 8 + lr) * 512 + kt * 64 + lcs);
      async16(lb + c * 512, W + (size_t)(colBase + c * 8 + lr) * 512 + kt * 64 + lcs);
    }
    __syncthreads();
    short8v af[2][4], bfr[2][4];
#pragma unroll
    for (int kk = 0; kk < 2; ++kk)
#pragma unroll
      for (int t = 0; t < 4; ++t) {
        int sl = ((kk * 4 + kb) ^ (li & 7)) << 3;   // swizzled read slot
        af[kk][t]  = *(const short8v*)(la + (wr * 64 + t * 16 + li) * 64 + sl);
        bfr[kk][t] = *(const short8v*)(lb + (wc * 64 + t * 16 + li) * 64 + sl);
      }
#pragma unroll
    for (int kk = 0; kk < 2; ++kk)
#pragma unroll
      for (int i = 0; i < 4; ++i)
#pragma unroll
        for (int j = 0; j < 4; ++j)
          acc[i][j] = MFMA_BF16(af[kk][i], bfr[kk][j], acc[i][j], 0, 0, 0);
    __syncthreads();
  }
  const int c0 = colBase + wc * 64;           // wave's first global col
  if (c0 >= 1024) {
    // ---- V block: transpose 64x64 subtile via private LDS, store p-contiguous ----
    ushort_t* tw = (w < 2) ? (la + w * 4096) : (lb + (w - 2) * 4096);
    char* twb = (char*)tw;
#pragma unroll
    for (int j = 0; j < 4; ++j) {
      int dloc = j * 16 + li;
      float bv = bias[c0 + dloc];
#pragma unroll
      for (int i = 0; i < 4; ++i) {
        unsigned u0 = pk2(acc[i][j][0] + bv, acc[i][j][1] + bv);
        unsigned u1 = pk2(acc[i][j][2] + bv, acc[i][j][3] + bv);
        int s = i * 2 + (kb >> 1);
        int byte = dloc * 128 + ((s ^ (dloc & 7)) << 4) + ((kb & 1) << 3);
        *(uint2*)(twb + byte) = make_uint2(u0, u1);
      }
    }
    const int h = (c0 - 1024) >> 6;
    const size_t nh = (size_t)((rowBase >> 9) * 8 + h);
    const int pbase = ((rowBase + wr * 64) & 511) + ((lane & 7) << 3);
    ushort_t* vb = Vt + nh * 32768 + pbase;
#pragma unroll
    for (int ps = 0; ps < 8; ++ps) {
      int dloc = ps * 8 + (lane >> 3);
      int byte = dloc * 128 + ((((lane & 7)) ^ (dloc & 7)) << 4);
      short8v vv = *(const short8v*)(twb + byte);
      *(short8v*)(vb + dloc * 512) = vv;
    }
  } else {
    // ---- Q/K block: original store path ----
#pragma unroll
    for (int j = 0; j < 4; ++j) {
      int colb = c0 + j * 16;
      int col = colb + li;
      float bv = bias[col];
      int c3 = colb >> 9;
      int h = (col >> 6) & 7;
      int d = col & 63;
#pragma unroll
      for (int i = 0; i < 4; ++i) {
        int m0 = rowBase + wr * 64 + i * 16 + kb * 4;
#pragma unroll
        for (int r = 0; r < 4; ++r) {
          int m = m0 + r;
          int n = m >> 9, p = m & 511;
          unsigned short bv16 = f2bf(acc[i][j][r] + bv);
          size_t nh = (size_t)(n * 8 + h);
          if (c3 == 0) Q [(nh * 512 + p) * 64 + d] = bv16;
          else         Ko[(nh * 512 + p) * 64 + d] = bv16;
        }
      }
    }
  }
}

// ---------------- flash attention: 2 q-tiles/wave, gload_lds dbuf, 1 barrier ----
// block = (nh, 128 q-rows); wave = 32 q-rows (2 tiles of 16). Swapped QK^T.
// K/V staged via global_load_lds into [64][64] with T2 XOR swizzle (linear LDS
// dest, pre-swizzled source col, swizzled read slot). Defer-max (T13).

#define TILE_SOFTMAX(S, M, L, OACC, PB) do {                                   \
  float ta = fmaxf(fmaxf(S[0][0], S[0][1]), S[0][2]);                          \
  float tb = fmaxf(fmaxf(S[0][3], S[1][0]), S[1][1]);                          \
  float tc = fmaxf(fmaxf(S[1][2], S[1][3]), S[2][0]);                          \
  float td = fmaxf(fmaxf(S[2][1], S[2][2]), S[2][3]);                          \
  float te = fmaxf(fmaxf(S[3][0], S[3][1]), S[3][2]);                          \
  float pm = fmaxf(fmaxf(fmaxf(ta, tb), fmaxf(tc, td)), fmaxf(te, S[3][3]));   \
  pm = fmaxf(pm, __shfl_xor(pm, 16, 64));                                      \
  pm = fmaxf(pm, __shfl_xor(pm, 32, 64));                                      \
  float scv = 1.0f;                                                            \
  if (!__all(pm <= M + 16.0f)) {                                               \
    float mn = fmaxf(M, pm);                                                   \
    scv = exp2f((M - mn) * cs);                                                \
    M = mn;                                                                    \
    float sr4[4];                                                              \
    _Pragma("unroll")                                                          \
    for (int r = 0; r < 4; ++r) sr4[r] = __shfl(scv, (kb << 2) + r, 16);       \
    _Pragma("unroll")                                                          \
    for (int dt = 0; dt < 4; ++dt)                                             \
      _Pragma("unroll")                                                        \
      for (int r = 0; r < 4; ++r) OACC[dt][r] *= sr4[r];                       \
  }                                                                            \
  const float nm = -M * cs;                                                    \
  float rs = 0.f;                                                              \
  _Pragma("unroll")                                                            \
  for (int t = 0; t < 4; ++t)                                                  \
    _Pragma("unroll")                                                          \
    for (int r = 0; r < 4; ++r) {                                              \
      float ev = exp2f(fmaf(S[t][r], cs, nm));                                 \
      S[t][r] = ev; rs += ev;                                                  \
    }                                                                          \
  rs += __shfl_xor(rs, 16, 64);                                                \
  rs += __shfl_xor(rs, 32, 64);                                                \
  L = fmaf(L, scv, rs);                                                        \
  _Pragma("unroll")                                                            \
  for (int t = 0; t < 4; ++t) {                                                \
    unsigned plo = pk2(S[t][0], S[t][1]);                                      \
    unsigned phi = pk2(S[t][2], S[t][3]);                                      \
    *(uint2*)((PB) + li * 72 + t * 16 + kb * 4) = make_uint2(plo, phi);        \
  }                                                                            \
} while (0)

__global__ __launch_bounds__(256, 2) void attn_kernel(const ushort_t* __restrict__ Q,
    const ushort_t* __restrict__ K, const ushort_t* __restrict__ Vt,
    const int* __restrict__ perm, ushort_t* __restrict__ O)
{
  __shared__ __align__(16) ushort_t kbuf[2][64][64];
  __shared__ __align__(16) ushort_t vbuf[2][64][64];
  __shared__ __align__(16) ushort_t pbuf[4][2][16][72];
  const int b = blockIdx.x;                   // 4096 = 128 nh-grp x 4 qc x 8 xcd
  const int qc = (b >> 3) & 3;
  const int nh = ((b >> 5) << 3) | (b & 7);
  const int n = nh >> 3, h = nh & 7;
  const int tid = threadIdx.x, w = tid >> 6, lane = tid & 63;
  const int li = lane & 15, kb = lane >> 4;
  const ushort_t* Qb = Q + (size_t)nh * (512 * 64);
  const ushort_t* Kb = K + (size_t)nh * (512 * 64);
  const ushort_t* Vb = Vt + (size_t)nh * (64 * 512);
  const int p0 = qc * 128 + w * 32;           // tile A rows p0.., tile B p0+16..

  // staging source (pre-swizzled col per rule #21)
  const int srow = lane >> 3;                 // 0..7
  const int ssw = (((lane & 7) ^ srow) << 3);
  const ushort_t* Ksrc = Kb + (size_t)(w * 8 + srow) * 64 + ssw;
  const ushort_t* Vsrc = Vb + (size_t)(w * 8 + srow) * 512 + ssw;

  short8v qa0 = *(const short8v*)(Qb + (size_t)(p0 + li) * 64 + kb * 8);
  short8v qa1 = *(const short8v*)(Qb + (size_t)(p0 + li) * 64 + 32 + kb * 8);
  short8v qb0 = *(const short8v*)(Qb + (size_t)(p0 + 16 + li) * 64 + kb * 8);
  short8v qb1 = *(const short8v*)(Qb + (size_t)(p0 + 16 + li) * 64 + 32 + kb * 8);

  f32x4 oa[4] = {}, ob[4] = {};
  float ma = -1e30f, la_ = 0.f, mb = -1e30f, lb_ = 0.f;
  const float cs = 0.125f * 1.44269504088896340736f;  // scale * log2(e)
  ushort_t* pbA = &pbuf[w][0][0][0];
  ushort_t* pbB = &pbuf[w][1][0][0];
  const int sl0 = (kb ^ (li & 7)) << 3;         // swizzled read slots
  const int sl1 = ((kb + 4) ^ (li & 7)) << 3;

  // prologue: stage chunk 0 into buf 0
  async16(&kbuf[0][w * 8][0], Ksrc);
  async16(&kbuf[0][w * 8 + 32][0], Ksrc + 2048);
  async16(&vbuf[0][w * 8][0], Vsrc);
  async16(&vbuf[0][w * 8 + 32][0], Vsrc + 16384);
  __syncthreads();

#pragma unroll
  for (int ch = 0; ch < 8; ++ch) {
    const int bi = ch & 1;
    if (ch < 7) {   // stage next chunk into the other buffer (drained at barrier)
      async16(&kbuf[bi ^ 1][w * 8][0], Ksrc + (size_t)(ch + 1) * 4096);
      async16(&kbuf[bi ^ 1][w * 8 + 32][0], Ksrc + (size_t)(ch + 1) * 4096 + 2048);
      async16(&vbuf[bi ^ 1][w * 8][0], Vsrc + (ch + 1) * 64);
      async16(&vbuf[bi ^ 1][w * 8 + 32][0], Vsrc + (ch + 1) * 64 + 16384);
    }
    // ---- tile A: QK^T ----
    {
      f32x4 s4[4];
#pragma unroll
      for (int t = 0; t < 4; ++t) {
        short8v kf0 = *(const short8v*)(&kbuf[bi][t * 16 + li][sl0]);
        short8v kf1 = *(const short8v*)(&kbuf[bi][t * 16 + li][sl1]);
        f32x4 z = {0.f, 0.f, 0.f, 0.f};
        z = MFMA_BF16(kf0, qa0, z, 0, 0, 0);
        z = MFMA_BF16(kf1, qa1, z, 0, 0, 0);
        s4[t] = z;
      }
      TILE_SOFTMAX(s4, ma, la_, oa, pbA);
    }
    // ---- tile B: QK^T ----
    {
      f32x4 s4[4];
#pragma unroll
      for (int t = 0; t < 4; ++t) {
        short8v kf0 = *(const short8v*)(&kbuf[bi][t * 16 + li][sl0]);
        short8v kf1 = *(const short8v*)(&kbuf[bi][t * 16 + li][sl1]);
        f32x4 z = {0.f, 0.f, 0.f, 0.f};
        z = MFMA_BF16(kf0, qb0, z, 0, 0, 0);
        z = MFMA_BF16(kf1, qb1, z, 0, 0, 0);
        s4[t] = z;
      }
      TILE_SOFTMAX(s4, mb, lb_, ob, pbB);
    }
    short8v pa0 = *(const short8v*)(pbA + li * 72 + kb * 8);
    short8v pa1 = *(const short8v*)(pbA + li * 72 + 32 + kb * 8);
    short8v pb0 = *(const short8v*)(pbB + li * 72 + kb * 8);
    short8v pb1 = *(const short8v*)(pbB + li * 72 + 32 + kb * 8);
    // ---- PV both tiles (vf shared) ----
#pragma unroll
    for (int dt = 0; dt < 4; ++dt) {
      short8v vf0 = *(const short8v*)(&vbuf[bi][dt * 16 + li][sl0]);
      short8v vf1 = *(const short8v*)(&vbuf[bi][dt * 16 + li][sl1]);
      oa[dt] = MFMA_BF16(pa0, vf0, oa[dt], 0, 0, 0);
      oa[dt] = MFMA_BF16(pa1, vf1, oa[dt], 0, 0, 0);
      ob[dt] = MFMA_BF16(pb0, vf0, ob[dt], 0, 0, 0);
      ob[dt] = MFMA_BF16(pb1, vf1, ob[dt], 0, 0, 0);
    }
    __syncthreads();
  }
  // epilogue, tile A then tile B
  {
    float iv = 1.0f / la_;
    float iv4[4];
#pragma unroll
    for (int r = 0; r < 4; ++r) iv4[r] = __shfl(iv, (kb << 2) + r, 16);
    int op[4];
#pragma unroll
    for (int r = 0; r < 4; ++r) op[r] = perm[n * 512 + p0 + kb * 4 + r];
#pragma unroll
    for (int dt = 0; dt < 4; ++dt)
#pragma unroll
      for (int r = 0; r < 4; ++r)
        O[(size_t)op[r] * 512 + h * 64 + dt * 16 + li] = f2bf(oa[dt][r] * iv4[r]);
  }
  {
    float iv = 1.0f / lb_;
    float iv4[4];
#pragma unroll
    for (int r = 0; r < 4; ++r) iv4[r] = __shfl(iv, (kb << 2) + r, 16);
    int op[4];
#pragma unroll
    for (int r = 0; r < 4; ++r) op[r] = perm[n * 512 + p0 + 16 + kb * 4 + r];
#pragma unroll
    for (int dt = 0; dt < 4; ++dt)
#pragma unroll
      for (int r = 0; r < 4; ++r)
        O[(size_t)op[r] * 512 + h * 64 + dt * 16 + li] = f2bf(ob[dt][r] * iv4[r]);
  }
}

// ---------------- proj GEMM (bf16), T2-swizzled LDS ----------------

__global__ __launch_bounds__(256) void proj_gemm(const ushort_t* __restrict__ A,
    const ushort_t* __restrict__ W, const float* __restrict__ bias,
    float* __restrict__ out)
{
  __shared__ __align__(16) ushort_t la[128 * 64];
  __shared__ __align__(16) ushort_t lb[128 * 64];
  const int bid = blockIdx.x;                 // 2048 = 4 x 512, XCD-chunked
  const int swz = (bid & 7) * 256 + (bid >> 3);
  const int bx = swz & 3, by = swz >> 2;
  const int rowBase = by * 128, colBase = bx * 128;
  const int tid = threadIdx.x, lane = tid & 63, w = tid >> 6;
  const int wr = w >> 1, wc = w & 1;
  const int li = lane & 15, kb = lane >> 4;
  const int lr = lane >> 3;
  const int lcs = (((lane & 7) ^ lr) << 3);
  f32x4 acc[4][4] = {};
  for (int kt = 0; kt < 8; ++kt) {
#pragma unroll
    for (int i = 0; i < 4; ++i) {
      int c = w * 4 + i;
      async16(la + c * 512, A + (size_t)(rowBase + c * 8 + lr) * 512 + kt * 64 + lcs);
      async16(lb + c * 512, W + (size_t)(colBase + c * 8 + lr) * 512 + kt * 64 + lcs);
    }
    __syncthreads();
    short8v af[2][4], bfr[2][4];
#pragma unroll
    for (int kk = 0; kk < 2; ++kk)
#pragma unroll
      for (int t = 0; t < 4; ++t) {
        int sl = ((kk * 4 + kb) ^ (li & 7)) << 3;
        af[kk][t]  = *(const short8v*)(la + (wr * 64 + t * 16 + li) * 64 + sl);
        bfr[kk][t] = *(const short8v*)(lb + (wc * 64 + t * 16 + li) * 64 + sl);
      }
#pragma unroll
    for (int kk = 0; kk < 2; ++kk)
#pragma unroll
      for (int i = 0; i < 4; ++i)
#pragma unroll
        for (int j = 0; j < 4; ++j)
          acc[i][j] = MFMA_BF16(af[kk][i], bfr[kk][j], acc[i][j], 0, 0, 0);
    __syncthreads();
  }
#pragma unroll
  for (int i = 0; i < 4; ++i)
#pragma unroll
    for (int j = 0; j < 4; ++j) {
      int col = colBase + wc * 64 + j * 16 + li;
      float bv = bias[col];
#pragma unroll
      for (int r = 0; r < 4; ++r) {
        int m = rowBase + wr * 64 + i * 16 + kb * 4 + r;
        out[(size_t)m * 512 + col] = acc[i][j][r] + bv;
      }
    }
}

// ---------------- launch ----------------

extern "C" void kernel_launch(void* const* d_in, const int* in_sizes, int n_in,
                              void* d_out, int out_size, void* d_ws, size_t ws_size,
                              hipStream_t stream) {
  (void)in_sizes; (void)n_in; (void)out_size; (void)ws_size;
  const float* feats      = (const float*)d_in[0];
  const int* codes        = (const int*)d_in[1];   // int64 in reference, delivered as int32
  const float* Wqkv       = (const float*)d_in[2];
  const float* bqkv       = (const float*)d_in[3];
  const float* Wproj      = (const float*)d_in[4];
  const float* bproj      = (const float*)d_in[5];
  float* out = (float*)d_out;

  char* ws = (char*)d_ws;
  int* perm = (int*)(ws);
  u64* keys = (u64*)(ws + 262144);
  ushort_t* Abf     = (ushort_t*)(ws + 1048576);                       // 64 MB
  ushort_t* att     = Abf;                                             // reuse
  ushort_t* Wqkvbf  = (ushort_t*)(ws + 1048576 + 67108864);            // 1.5 MB
  ushort_t* Wprojbf = (ushort_t*)(ws + 1048576 + 67108864 + 1572864);  // 0.5 MB
  ushort_t* Qb      = (ushort_t*)(ws + 1048576 + 67108864 + 2097152);
  ushort_t* Kb      = Qb + 33554432ull;
  ushort_t* Vt      = Kb + 33554432ull;

  sort_chunk<<<16, 512, 0, stream>>>(codes, keys);
  sort_gpass<<<256, 256, 0, stream>>>(keys, 8192, 4096);
  sort_finish<<<16, 512, 0, stream>>>(keys, 8192);
  sort_gpass<<<256, 256, 0, stream>>>(keys, 16384, 8192);
  sort_gpass<<<256, 256, 0, stream>>>(keys, 16384, 4096);
  sort_finish<<<16, 512, 0, stream>>>(keys, 16384);
  write_perm<<<256, 256, 0, stream>>>(keys, perm);

  gather_bf16<<<8192, 256, 0, stream>>>(feats, perm, Abf);
  convert_bf16<<<384, 256, 0, stream>>>(Wqkv, Wqkvbf);
  convert_bf16<<<128, 256, 0, stream>>>(Wproj, Wprojbf);

  qkv_gemm<<<6144, 256, 0, stream>>>(Abf, Wqkvbf, bqkv, Qb, Kb, Vt);
  attn_kernel<<<4096, 256, 0, stream>>>(Qb, Kb, Vt, perm, att);
  proj_gemm<<<2048, 256, 0, stream>>>(att, Wprojbf, bproj, out);
}